// Round 5
// baseline (304.127 us; speedup 1.0000x reference)
//
#include <hip/hip_runtime.h>
#include <hip/hip_bf16.h>
#include <math.h>

#define B_ 2
#define L_ 2048
#define D_ 1024
#define K_ 32
#define M_ 4
#define H_ 32
#define AH_ 4
#define DH_ 28
#define CK_ 4
#define TOTAL_ 2208
#define NPAD_ 2304
#define BL_ (B_*L_)
#define CL_ 16
#define NC_ (L_/CL_)
#define CTS_ 280   // ct row stride (ushorts)
#define ZS_ 72     // zck row stride (floats): xv 0-31, gate 32-63, s 64, pad, theta 68-71

typedef __attribute__((ext_vector_type(8))) short bf16x8;
typedef __attribute__((ext_vector_type(4))) float f32x4;

static __device__ inline unsigned short f2bu(float f) {
    union { __hip_bfloat16 h; unsigned short u; } cv;
    cv.h = __float2bfloat16(f);
    return cv.u;
}
static __device__ inline float b2f(unsigned short u) {
    union { unsigned short u; __hip_bfloat16 h; } cv;
    cv.u = u;
    return __bfloat162float(cv.h);
}

// ---------- x -> bf16 ----------
__global__ void convert_x(const float4* __restrict__ src, ushort* __restrict__ dst) {
    int i = blockIdx.x * 256 + threadIdx.x;
    float4 v = src[i];
    ushort4 o;
    o.x = f2bu(v.x); o.y = f2bu(v.y); o.z = f2bu(v.z); o.w = f2bu(v.w);
    *(ushort4*)(dst + (size_t)i * 4) = o;
}

// ---------- transpose fp32 [K][N] -> bf16 [Npad][K] (zero-pad rows >= N) ----
__global__ void transpose_bf16_pad(const float* __restrict__ src, ushort* __restrict__ dst,
                                   int K, int N) {
    __shared__ float tile[64][65];
    int n0 = blockIdx.x * 64, k0 = blockIdx.y * 64;
    int t = threadIdx.x;
#pragma unroll
    for (int i = 0; i < 16; ++i) {
        int idx = t + i * 256;
        int r = idx >> 6, c = idx & 63;
        int gn = n0 + c;
        tile[r][c] = (gn < N) ? src[(size_t)(k0 + r) * N + gn] : 0.f;
    }
    __syncthreads();
#pragma unroll
    for (int i = 0; i < 16; ++i) {
        int idx = t + i * 256;
        int r = idx >> 6, c = idx & 63;
        dst[(size_t)(n0 + r) * K + k0 + c] = f2bu(tile[c][r]);
    }
}

// ---------- W'' prep: W2B[hout][ch] = nscale[ch] * (ch<128 ? Wre : Wim) -----
__global__ void prep_w2(const float* __restrict__ Wre, const float* __restrict__ Wim,
                        const float* __restrict__ nscale, ushort* __restrict__ W2B) {
    int ch = threadIdx.x;  // 256
    float ns = nscale[ch];
    for (int hout = 0; hout < 32; ++hout) {
        float w = (ch < 128) ? Wre[ch * 32 + hout] : Wim[(ch - 128) * 32 + hout];
        W2B[hout * 256 + ch] = f2bu(ns * w);
    }
}

// ---------- bf16 MFMA GEMM: C[M,N] = A[M,Kd] @ Bt[N,Kd]^T, C fp32 ------------
__global__ __launch_bounds__(256) void gemm_bt(const ushort* __restrict__ A,
                                               const ushort* __restrict__ Bt,
                                               float* __restrict__ C,
                                               int Kd, int ldc) {
    __shared__ __align__(16) ushort As[128 * 32];
    __shared__ __align__(16) ushort Bs[128 * 32];
    int tid = threadIdx.x;
    int wave = tid >> 6, lane = tid & 63;
    int quad = lane >> 4, l16 = lane & 15;
    int m0 = blockIdx.y * 128, n0 = blockIdx.x * 128;
    int wm = (wave >> 1) * 64, wn = (wave & 1) * 64;
    f32x4 acc[4][4];
#pragma unroll
    for (int i = 0; i < 4; ++i)
#pragma unroll
        for (int j = 0; j < 4; ++j) acc[i][j] = (f32x4){0.f, 0.f, 0.f, 0.f};

    int swzq = quad ^ (l16 & 3);

    for (int k0 = 0; k0 < Kd; k0 += 32) {
#pragma unroll
        for (int i = 0; i < 2; ++i) {
            int s = i * 256 + tid;
            int row = s >> 2;
            int qg = (s & 3) ^ (row & 3);
            const ushort* ga = A + (size_t)(m0 + row) * Kd + k0 + qg * 8;
            const ushort* gb = Bt + (size_t)(n0 + row) * Kd + k0 + qg * 8;
            __builtin_amdgcn_global_load_lds((const __attribute__((address_space(1))) void*)ga,
                                             (__attribute__((address_space(3))) void*)(As + (size_t)s * 8),
                                             16, 0, 0);
            __builtin_amdgcn_global_load_lds((const __attribute__((address_space(1))) void*)gb,
                                             (__attribute__((address_space(3))) void*)(Bs + (size_t)s * 8),
                                             16, 0, 0);
        }
        __syncthreads();
        bf16x8 af[4], bfr[4];
#pragma unroll
        for (int mi = 0; mi < 4; ++mi)
            af[mi] = *(const bf16x8*)(As + (size_t)(wm + mi * 16 + l16) * 32 + swzq * 8);
#pragma unroll
        for (int ni = 0; ni < 4; ++ni)
            bfr[ni] = *(const bf16x8*)(Bs + (size_t)(wn + ni * 16 + l16) * 32 + swzq * 8);
#pragma unroll
        for (int mi = 0; mi < 4; ++mi)
#pragma unroll
            for (int ni = 0; ni < 4; ++ni)
                acc[mi][ni] = __builtin_amdgcn_mfma_f32_16x16x32_bf16(af[mi], bfr[ni], acc[mi][ni], 0, 0, 0);
        __syncthreads();
    }
#pragma unroll
    for (int mi = 0; mi < 4; ++mi)
#pragma unroll
        for (int ni = 0; ni < 4; ++ni)
#pragma unroll
            for (int r = 0; r < 4; ++r) {
                int gm = m0 + wm + mi * 16 + quad * 4 + r;
                int gn = n0 + wn + ni * 16 + l16;
                C[(size_t)gm * ldc + gn] = acc[mi][ni][r];
            }
}

// ---------- causal depthwise conv + K-major relayout -------------------------
__global__ void conv_kernel(const float* __restrict__ z, const float* __restrict__ cw,
                            const float* __restrict__ cb, float* __restrict__ zck) {
    int t = blockIdx.x * 256 + threadIdx.x;
    if (t >= BL_ * (TOTAL_ / 4)) return;
    int c4 = (t % (TOTAL_ / 4)) * 4;
    int bl = t / (TOTAL_ / 4);
    int l = bl % L_, b = bl / L_;
    float4 acc = *(const float4*)(cb + c4);
#pragma unroll
    for (int tap = 0; tap < CK_; ++tap) {
        int ls = l - (CK_ - 1) + tap;
        if (ls >= 0) {
            float4 zv = *(const float4*)(z + (size_t)(bl - (CK_ - 1) + tap) * NPAD_ + c4);
            float4 wv = *(const float4*)(cw + tap * TOTAL_ + c4);
            acc.x = fmaf(zv.x, wv.x, acc.x);
            acc.y = fmaf(zv.y, wv.y, acc.y);
            acc.z = fmaf(zv.z, wv.z, acc.z);
            acc.w = fmaf(zv.w, wv.w, acc.w);
        }
    }
    if (c4 < D_) {
        int k = c4 >> 5, slot = c4 & 31;
        *(float4*)(zck + ((size_t)(b * K_ + k) * L_ + l) * ZS_ + slot) = acc;
    } else if (c4 < 2 * D_) {
        int cc = c4 - D_;
        int k = cc >> 5, slot = 32 + (cc & 31);
        *(float4*)(zck + ((size_t)(b * K_ + k) * L_ + l) * ZS_ + slot) = acc;
    } else if (c4 < 2 * D_ + K_) {
        float av[4] = {acc.x, acc.y, acc.z, acc.w};
#pragma unroll
        for (int q = 0; q < 4; ++q) {
            int k = c4 + q - 2 * D_;
            zck[((size_t)(b * K_ + k) * L_ + l) * ZS_ + 64] = av[q];
        }
    } else {
        int j = c4 - (2 * D_ + K_);
        int k = j >> 2;
        *(float4*)(zck + ((size_t)(b * K_ + k) * L_ + l) * ZS_ + 68) = acc;
    }
}

// ---------- pass1: chunk sums + contributions -> LDS -> vc via MFMA ----------
__global__ __launch_bounds__(128) void pass1(const float* __restrict__ zck,
                                             const float* __restrict__ mask,
                                             const float* __restrict__ theta_base,
                                             const float* __restrict__ trs_,
                                             const float* __restrict__ dslopes,
                                             const float* __restrict__ aslopes,
                                             const float* __restrict__ sscale_,
                                             const ushort* __restrict__ W2B,
                                             float* __restrict__ cs_re,
                                             float* __restrict__ cs_im,
                                             float* __restrict__ cs_den,
                                             float* __restrict__ vc) {
    __shared__ __align__(16) ushort ct[CL_ * CTS_];
    int nc = blockIdx.x, k = blockIdx.y, b = blockIdx.z;
    int hm = threadIdx.x;
    int h = hm >> 2, m = hm & 3;
    int bk = b * K_ + k;
    size_t bkL = (size_t)bk * L_;
    float raw = (k < DH_) ? dslopes[k] : aslopes[k - DH_];
    float slope = log1pf(__expf(raw));
    float sscale = sscale_[k];
    float trsv = trs_[k];
    float tb = theta_base[k * M_ + m];
    const float PI3 = 1.04719755119659775f;
    float are = 0.f, aim = 0.f, aden = 0.f;
    int l0 = nc * CL_;
#pragma unroll 4
    for (int i = 0; i < CL_; ++i) {
        int l = l0 + i;
        const float* zrow = zck + (bkL + l) * ZS_;
        float mval = mask[b * L_ + l];
        float s_raw = zrow[64] * mval;
        float tr = zrow[68 + m];
        float xv = zrow[h] * mval;
        float arg = fminf(fmaxf(sscale * s_raw, -20.f), 20.f);
        float p = __expf(arg) * mval;
        float tw = (k < DH_) ? __expf(-slope * (float)(L_ - 1 - l)) : __expf(-slope * (float)l);
        float pw = p * tw;
        float td = tr / (1.f + fabsf(tr));
        float theta = tb + trsv * (td * PI3);
        float phi = xv * theta;
        float sv = __sinf(phi), cv = __cosf(phi);
        unsigned short cu_re = f2bu(pw * cv);
        unsigned short cu_im = f2bu(pw * sv);
        are += b2f(cu_re); aim += b2f(cu_im); aden += pw;
        ct[i * CTS_ + hm] = cu_re;
        ct[i * CTS_ + 128 + hm] = cu_im;
    }
    size_t o = ((size_t)(bk * NC_ + nc)) * 128 + hm;
    cs_re[o] = are;
    cs_im[o] = aim;
    if (hm == 0) cs_den[bk * NC_ + nc] = aden;
    __syncthreads();
    // phase B: vc[l, hout] = C_chunk(16x256) @ W''(256x32); wave w -> hout tile w
    int wave = hm >> 6, lane = hm & 63;
    int quad = lane >> 4, l16 = lane & 15;
    f32x4 acc = (f32x4){0.f, 0.f, 0.f, 0.f};
#pragma unroll
    for (int ks = 0; ks < 8; ++ks) {
        bf16x8 af = *(const bf16x8*)(ct + (size_t)l16 * CTS_ + ks * 32 + quad * 8);
        bf16x8 bfr = *(const bf16x8*)(W2B + (size_t)(wave * 16 + l16) * 256 + ks * 32 + quad * 8);
        acc = __builtin_amdgcn_mfma_f32_16x16x32_bf16(af, bfr, acc, 0, 0, 0);
    }
    size_t vbase = (bkL + l0) * 32;
#pragma unroll
    for (int r = 0; r < 4; ++r) {
        int row = quad * 4 + r;
        vc[vbase + (size_t)row * 32 + wave * 16 + l16] = acc[r];
    }
}

// ---------- pass2: exclusive scan of chunk sums ------------------------------
__global__ void pass2(float* cs_re, float* cs_im, float* cs_den) {
    int seq = blockIdx.x * 256 + threadIdx.x;
    if (seq >= B_ * K_ * 257) return;
    int bk = seq / 257;
    int ch = seq % 257;
    float* base;
    int stride;
    if (ch < 128) { base = cs_re + (size_t)bk * NC_ * 128 + ch; stride = 128; }
    else if (ch < 256) { base = cs_im + (size_t)bk * NC_ * 128 + (ch - 128); stride = 128; }
    else { base = cs_den + (size_t)bk * NC_; stride = 1; }
    float run = 0.f;
#pragma unroll 4
    for (int i = 0; i < NC_; ++i) {
        float v = base[(size_t)i * stride];
        base[(size_t)i * stride] = run;
        run += v;
    }
}

// ---------- scan: fused u_prev matvec + barrier-free scan + gate + store -----
__global__ __launch_bounds__(64) void scan_kernel(const float* __restrict__ zck,
                                                  const float* __restrict__ mask,
                                                  const float* __restrict__ theta_base,
                                                  const float* __restrict__ trs_,
                                                  const float* __restrict__ dslopes,
                                                  const float* __restrict__ aslopes,
                                                  const float* __restrict__ sscale_,
                                                  const ushort* __restrict__ W2B,
                                                  const float* __restrict__ cs_re,
                                                  const float* __restrict__ cs_im,
                                                  const float* __restrict__ cs_den,
                                                  const float* __restrict__ vc,
                                                  ushort* __restrict__ gq) {
    int nc = blockIdx.x, k = blockIdx.y, b = blockIdx.z;
    int lane = threadIdx.x;
    int bk = b * K_ + k;
    size_t bkL = (size_t)bk * L_;
    int h0 = lane >> 2, h1 = 16 + (lane >> 2), m = lane & 3;
    int hout = lane & 31, half = lane >> 5;
    float raw = (k < DH_) ? dslopes[k] : aslopes[k - DH_];
    float slope = log1pf(__expf(raw));
    float sscale = sscale_[k];
    float trsv = trs_[k];
    float tb = theta_base[k * M_ + m];
    const float PI3 = 1.04719755119659775f;

    size_t o = ((size_t)(bk * NC_ + nc)) * 128;
    // u_prev = dot(A_prev, W''[:,hout]) — cs reads are wave-uniform
    const float* srcp = half ? (cs_im + o) : (cs_re + o);
    float u = 0.f;
#pragma unroll 8
    for (int i = 0; i < 128; ++i)
        u = fmaf(srcp[i], b2f(W2B[hout * 256 + half * 128 + i]), u);
    u += __shfl_xor(u, 32, 64);

    float are0 = cs_re[o + lane];
    float are1 = cs_re[o + 64 + lane];
    float aim0 = cs_im[o + lane];
    float aim1 = cs_im[o + 64 + lane];
    float den = cs_den[bk * NC_ + nc];
    int l0 = nc * CL_;

#pragma unroll 4
    for (int i = 0; i < CL_; ++i) {
        int l = l0 + i;
        const float* zrow = zck + (bkL + l) * ZS_;
        float mval = mask[b * L_ + l];
        float s_raw = zrow[64] * mval;
        float tr = zrow[68 + m];
        float xv0 = zrow[h0] * mval;
        float xv1 = zrow[h1] * mval;
        float arg = fminf(fmaxf(sscale * s_raw, -20.f), 20.f);
        float p = __expf(arg) * mval;
        float tw = (k < DH_) ? __expf(-slope * (float)(L_ - 1 - l)) : __expf(-slope * (float)l);
        float pw = p * tw;
        float td = tr / (1.f + fabsf(tr));
        float theta = tb + trsv * (td * PI3);
        float s0 = __sinf(xv0 * theta), c0 = __cosf(xv0 * theta);
        float s1 = __sinf(xv1 * theta), c1 = __cosf(xv1 * theta);
        // bf16-round to match pass1's sums exactly
        float cre0 = b2f(f2bu(pw * c0)), cim0 = b2f(f2bu(pw * s0));
        float cre1 = b2f(f2bu(pw * c1)), cim1 = b2f(f2bu(pw * s1));
        are0 += cre0; aim0 += cim0; are1 += cre1; aim1 += cim1;
        den += pw;
        float s = are0 * are0 + are1 * are1 + aim0 * aim0 + aim1 * aim1;
#pragma unroll
        for (int off = 32; off; off >>= 1) s += __shfl_xor(s, off, 64);
        float inv = 1.f / fmaxf(den, 1e-4f);
        float rsq = rsqrtf(inv * inv * s * (1.0f / 256.0f) + 1e-5f);
        float scv = inv * rsq;
        u += vc[(bkL + l) * 32 + hout];
        float y = scv * u;
        float zg = zrow[32 + hout];
        float gate = zg / (1.f + __expf(-zg));
        if (lane < 32) gq[(size_t)(b * L_ + l) * D_ + k * H_ + hout] = f2bu(y * gate);
    }
}

extern "C" void kernel_launch(void* const* d_in, const int* in_sizes, int n_in,
                              void* d_out, int out_size, void* d_ws, size_t ws_size,
                              hipStream_t stream) {
    const float* x = (const float*)d_in[0];
    const float* mask = (const float*)d_in[1];
    const float* W_in = (const float*)d_in[2];
    const float* conv_w = (const float*)d_in[3];
    const float* conv_b = (const float*)d_in[4];
    const float* theta_base = (const float*)d_in[5];
    const float* trs = (const float*)d_in[6];
    const float* dsl = (const float*)d_in[7];
    const float* asl = (const float*)d_in[8];
    const float* ssc = (const float*)d_in[9];
    const float* nsc = (const float*)d_in[10];
    const float* Wre = (const float*)d_in[11];
    const float* Wim = (const float*)d_in[12];
    const float* Wout = (const float*)d_in[13];
    float* out = (float*)d_out;

    char* ws = (char*)d_ws;
    // [0, 37.75M): zck
    float* zck = (float*)(ws);
    // [37.75M, 75.5M): z (dead after conv) -> cs_re/cs_im/cs_den/gq
    float* z      = (float*)(ws + 37748736ULL);
    float* cs_re  = (float*)(ws + 37748736ULL);   // 64*128*128*4 = 4,194,304
    float* cs_im  = (float*)(ws + 41943040ULL);   // 4,194,304
    float* cs_den = (float*)(ws + 46137344ULL);   // 32,768
    ushort* gq    = (ushort*)(ws + 46170112ULL);  // 8,388,608 (ends 54,558,720)
    // [75.5M, 88.6M): x_bf + Wt_in (dead after gemm1) -> vc [75.5M, 92.3M)
    ushort* x_bf  = (ushort*)(ws + 75497472ULL);
    ushort* Wt_in = (ushort*)(ws + 83886080ULL);
    float* vc     = (float*)(ws + 75497472ULL);
    // tail: Wt_o, W2B
    ushort* Wt_o  = (ushort*)(ws + 92274688ULL);
    ushort* W2B   = (ushort*)(ws + 94371840ULL);

    convert_x<<<4096, 256, 0, stream>>>((const float4*)x, x_bf);
    transpose_bf16_pad<<<dim3(NPAD_ / 64, 16), 256, 0, stream>>>(W_in, Wt_in, 1024, TOTAL_);
    transpose_bf16_pad<<<dim3(16, 16), 256, 0, stream>>>(Wout, Wt_o, 1024, 1024);
    prep_w2<<<1, 256, 0, stream>>>(Wre, Wim, nsc, W2B);
    gemm_bt<<<dim3(NPAD_ / 128, BL_ / 128), 256, 0, stream>>>(x_bf, Wt_in, z, 1024, NPAD_);
    conv_kernel<<<(BL_ * (TOTAL_ / 4) + 255) / 256, 256, 0, stream>>>(z, conv_w, conv_b, zck);
    pass1<<<dim3(NC_, K_, B_), 128, 0, stream>>>(zck, mask, theta_base, trs, dsl, asl, ssc,
                                                 W2B, cs_re, cs_im, cs_den, vc);
    pass2<<<(B_ * K_ * 257 + 255) / 256, 256, 0, stream>>>(cs_re, cs_im, cs_den);
    scan_kernel<<<dim3(NC_, K_, B_), 64, 0, stream>>>(zck, mask, theta_base, trs, dsl, asl, ssc,
                                                      W2B, cs_re, cs_im, cs_den, vc, gq);
    gemm_bt<<<dim3(D_ / 128, BL_ / 128), 256, 0, stream>>>(gq, Wt_o, out, 1024, 1024);
}

// Round 6
// 301.104 us; speedup vs baseline: 1.0100x; 1.0100x over previous
//
#include <hip/hip_runtime.h>
#include <hip/hip_bf16.h>
#include <math.h>

#define B_ 2
#define L_ 2048
#define D_ 1024
#define K_ 32
#define M_ 4
#define H_ 32
#define AH_ 4
#define DH_ 28
#define CK_ 4
#define TOTAL_ 2208
#define NPAD_ 2304
#define BL_ (B_*L_)
#define CL_ 16
#define NC_ (L_/CL_)
#define CTS_ 280   // ct row stride (ushorts)
#define ZS_ 72     // fallback zck row stride (floats)
#define ZS2_ 128   // fast zck2 row stride (floats): xv 0-31, s 32, theta 36-39

typedef __attribute__((ext_vector_type(8))) short bf16x8;
typedef __attribute__((ext_vector_type(4))) float f32x4;

static __device__ inline unsigned short f2bu(float f) {
    union { __hip_bfloat16 h; unsigned short u; } cv;
    cv.h = __float2bfloat16(f);
    return cv.u;
}
static __device__ inline float b2f(unsigned short u) {
    union { unsigned short u; __hip_bfloat16 h; } cv;
    cv.u = u;
    return __bfloat162float(cv.h);
}

// ---------- x -> bf16 ----------
__global__ void convert_x(const float4* __restrict__ src, ushort* __restrict__ dst) {
    int i = blockIdx.x * 256 + threadIdx.x;
    float4 v = src[i];
    ushort4 o;
    o.x = f2bu(v.x); o.y = f2bu(v.y); o.z = f2bu(v.z); o.w = f2bu(v.w);
    *(ushort4*)(dst + (size_t)i * 4) = o;
}

// ---------- transpose fp32 [K][N] -> bf16 [Npad][K] ----------
__global__ void transpose_bf16_pad(const float* __restrict__ src, ushort* __restrict__ dst,
                                   int K, int N) {
    __shared__ float tile[64][65];
    int n0 = blockIdx.x * 64, k0 = blockIdx.y * 64;
    int t = threadIdx.x;
#pragma unroll
    for (int i = 0; i < 16; ++i) {
        int idx = t + i * 256;
        int r = idx >> 6, c = idx & 63;
        int gn = n0 + c;
        tile[r][c] = (gn < N) ? src[(size_t)(k0 + r) * N + gn] : 0.f;
    }
    __syncthreads();
#pragma unroll
    for (int i = 0; i < 16; ++i) {
        int idx = t + i * 256;
        int r = idx >> 6, c = idx & 63;
        dst[(size_t)(n0 + r) * K + k0 + c] = f2bu(tile[c][r]);
    }
}

// ---------- W'' prep ----------
__global__ void prep_w2(const float* __restrict__ Wre, const float* __restrict__ Wim,
                        const float* __restrict__ nscale, ushort* __restrict__ W2B) {
    int ch = threadIdx.x;  // 256
    float ns = nscale[ch];
    for (int hout = 0; hout < 32; ++hout) {
        float w = (ch < 128) ? Wre[ch * 32 + hout] : Wim[(ch - 128) * 32 + hout];
        W2B[hout * 256 + ch] = f2bu(ns * w);
    }
}

// ---------- bf16 MFMA GEMM ----------
__global__ __launch_bounds__(256) void gemm_bt(const ushort* __restrict__ A,
                                               const ushort* __restrict__ Bt,
                                               float* __restrict__ C,
                                               int Kd, int ldc) {
    __shared__ __align__(16) ushort As[128 * 32];
    __shared__ __align__(16) ushort Bs[128 * 32];
    int tid = threadIdx.x;
    int wave = tid >> 6, lane = tid & 63;
    int quad = lane >> 4, l16 = lane & 15;
    int m0 = blockIdx.y * 128, n0 = blockIdx.x * 128;
    int wm = (wave >> 1) * 64, wn = (wave & 1) * 64;
    f32x4 acc[4][4];
#pragma unroll
    for (int i = 0; i < 4; ++i)
#pragma unroll
        for (int j = 0; j < 4; ++j) acc[i][j] = (f32x4){0.f, 0.f, 0.f, 0.f};

    int swzq = quad ^ (l16 & 3);

    for (int k0 = 0; k0 < Kd; k0 += 32) {
#pragma unroll
        for (int i = 0; i < 2; ++i) {
            int s = i * 256 + tid;
            int row = s >> 2;
            int qg = (s & 3) ^ (row & 3);
            const ushort* ga = A + (size_t)(m0 + row) * Kd + k0 + qg * 8;
            const ushort* gb = Bt + (size_t)(n0 + row) * Kd + k0 + qg * 8;
            __builtin_amdgcn_global_load_lds((const __attribute__((address_space(1))) void*)ga,
                                             (__attribute__((address_space(3))) void*)(As + (size_t)s * 8),
                                             16, 0, 0);
            __builtin_amdgcn_global_load_lds((const __attribute__((address_space(1))) void*)gb,
                                             (__attribute__((address_space(3))) void*)(Bs + (size_t)s * 8),
                                             16, 0, 0);
        }
        __syncthreads();
        bf16x8 af[4], bfr[4];
#pragma unroll
        for (int mi = 0; mi < 4; ++mi)
            af[mi] = *(const bf16x8*)(As + (size_t)(wm + mi * 16 + l16) * 32 + swzq * 8);
#pragma unroll
        for (int ni = 0; ni < 4; ++ni)
            bfr[ni] = *(const bf16x8*)(Bs + (size_t)(wn + ni * 16 + l16) * 32 + swzq * 8);
#pragma unroll
        for (int mi = 0; mi < 4; ++mi)
#pragma unroll
            for (int ni = 0; ni < 4; ++ni)
                acc[mi][ni] = __builtin_amdgcn_mfma_f32_16x16x32_bf16(af[mi], bfr[ni], acc[mi][ni], 0, 0, 0);
        __syncthreads();
    }
#pragma unroll
    for (int mi = 0; mi < 4; ++mi)
#pragma unroll
        for (int ni = 0; ni < 4; ++ni)
#pragma unroll
            for (int r = 0; r < 4; ++r) {
                int gm = m0 + wm + mi * 16 + quad * 4 + r;
                int gn = n0 + wn + ni * 16 + l16;
                C[(size_t)gm * ldc + gn] = acc[mi][ni][r];
            }
}

// ============================ FAST PATH =====================================

// conv + relayout: zck2 rows (128 f32): xv 0-31, s 32, theta 36-39.
// gate -> silu'd bf16 in gateb[bk][l][32].
__global__ void conv_fast(const float* __restrict__ z, const float* __restrict__ cw,
                          const float* __restrict__ cb, float* __restrict__ zck2,
                          ushort* __restrict__ gateb) {
    int t = blockIdx.x * 256 + threadIdx.x;
    if (t >= BL_ * (TOTAL_ / 4)) return;
    int c4 = (t % (TOTAL_ / 4)) * 4;
    int bl = t / (TOTAL_ / 4);
    int l = bl % L_, b = bl / L_;
    float4 acc = *(const float4*)(cb + c4);
#pragma unroll
    for (int tap = 0; tap < CK_; ++tap) {
        int ls = l - (CK_ - 1) + tap;
        if (ls >= 0) {
            float4 zv = *(const float4*)(z + (size_t)(bl - (CK_ - 1) + tap) * NPAD_ + c4);
            float4 wv = *(const float4*)(cw + tap * TOTAL_ + c4);
            acc.x = fmaf(zv.x, wv.x, acc.x);
            acc.y = fmaf(zv.y, wv.y, acc.y);
            acc.z = fmaf(zv.z, wv.z, acc.z);
            acc.w = fmaf(zv.w, wv.w, acc.w);
        }
    }
    if (c4 < D_) {
        int k = c4 >> 5, slot = c4 & 31;
        *(float4*)(zck2 + ((size_t)(b * K_ + k) * L_ + l) * ZS2_ + slot) = acc;
    } else if (c4 < 2 * D_) {
        int cc = c4 - D_;
        int k = cc >> 5, hh = cc & 31;
        float av[4] = {acc.x, acc.y, acc.z, acc.w};
        ushort4 o;
        unsigned short* op = (unsigned short*)&o;
#pragma unroll
        for (int q = 0; q < 4; ++q) {
            float zg = av[q];
            op[q] = f2bu(zg / (1.f + __expf(-zg)));
        }
        *(ushort4*)(gateb + ((size_t)(b * K_ + k) * L_ + l) * 32 + hh) = o;
    } else if (c4 < 2 * D_ + K_) {
        float av[4] = {acc.x, acc.y, acc.z, acc.w};
#pragma unroll
        for (int q = 0; q < 4; ++q) {
            int k = c4 + q - 2 * D_;
            zck2[((size_t)(b * K_ + k) * L_ + l) * ZS2_ + 32] = av[q];
        }
    } else {
        int j = c4 - (2 * D_ + K_);
        int k = j >> 2;
        *(float4*)(zck2 + ((size_t)(b * K_ + k) * L_ + l) * ZS2_ + 36) = acc;
    }
}

// pass1_fast: chunk sums + contributions; vc via MFMA; ctb written IN-PLACE over
// the block's own zck2 rows (all reads complete before writes). pw stored.
__global__ __launch_bounds__(128) void pass1_fast(const float* zck2,
                                                  const float* __restrict__ mask,
                                                  const float* __restrict__ theta_base,
                                                  const float* __restrict__ trs_,
                                                  const float* __restrict__ dslopes,
                                                  const float* __restrict__ aslopes,
                                                  const float* __restrict__ sscale_,
                                                  const ushort* __restrict__ W2B,
                                                  float* __restrict__ cs_re,
                                                  float* __restrict__ cs_im,
                                                  float* __restrict__ cs_den,
                                                  float* __restrict__ vc,
                                                  ushort* ctb,
                                                  float* __restrict__ pwb) {
    __shared__ __align__(16) ushort ct[CL_ * CTS_];
    int nc = blockIdx.x, k = blockIdx.y, b = blockIdx.z;
    int hm = threadIdx.x;
    int h = hm >> 2, m = hm & 3;
    int bk = b * K_ + k;
    size_t bkL = (size_t)bk * L_;
    float raw = (k < DH_) ? dslopes[k] : aslopes[k - DH_];
    float slope = log1pf(__expf(raw));
    float sscale = sscale_[k];
    float trsv = trs_[k];
    float tb = theta_base[k * M_ + m];
    const float PI3 = 1.04719755119659775f;
    float are = 0.f, aim = 0.f, aden = 0.f;
    int l0 = nc * CL_;
    float tw = (k < DH_) ? __expf(-slope * (float)(L_ - 1 - l0)) : __expf(-slope * (float)l0);
    float e_s = (k < DH_) ? __expf(slope) : __expf(-slope);
#pragma unroll 4
    for (int i = 0; i < CL_; ++i) {
        int l = l0 + i;
        const float* zrow = zck2 + (bkL + l) * ZS2_;
        float mval = mask[b * L_ + l];
        float s_raw = zrow[32] * mval;
        float tr = zrow[36 + m];
        float xv = zrow[h] * mval;
        float arg = fminf(fmaxf(sscale * s_raw, -20.f), 20.f);
        float p = __expf(arg) * mval;
        float pw = p * tw;
        float td = tr / (1.f + fabsf(tr));
        float theta = tb + trsv * (td * PI3);
        float phi = xv * theta;
        float sv = __sinf(phi), cv = __cosf(phi);
        unsigned short cu_re = f2bu(pw * cv);
        unsigned short cu_im = f2bu(pw * sv);
        are += b2f(cu_re); aim += b2f(cu_im); aden += pw;
        ct[i * CTS_ + hm] = cu_re;
        ct[i * CTS_ + 128 + hm] = cu_im;
        if (hm == 0) pwb[bkL + l] = pw;
        tw *= e_s;
    }
    size_t o = ((size_t)(bk * NC_ + nc)) * 128 + hm;
    cs_re[o] = are;
    cs_im[o] = aim;
    if (hm == 0) cs_den[bk * NC_ + nc] = aden;
    __syncthreads();
    // vc = C_chunk(16x256) @ W''(256x32); wave w -> hout tile w
    int wave = hm >> 6, lane = hm & 63;
    int quad = lane >> 4, l16 = lane & 15;
    f32x4 acc = (f32x4){0.f, 0.f, 0.f, 0.f};
#pragma unroll
    for (int ks = 0; ks < 8; ++ks) {
        bf16x8 af = *(const bf16x8*)(ct + (size_t)l16 * CTS_ + ks * 32 + quad * 8);
        bf16x8 bfr = *(const bf16x8*)(W2B + (size_t)(wave * 16 + l16) * 256 + ks * 32 + quad * 8);
        acc = __builtin_amdgcn_mfma_f32_16x16x32_bf16(af, bfr, acc, 0, 0, 0);
    }
    size_t vbase = (bkL + l0) * 32;
#pragma unroll
    for (int r = 0; r < 4; ++r) {
        int row = quad * 4 + r;
        vc[vbase + (size_t)row * 32 + wave * 16 + l16] = acc[r];
    }
    // write ctb rows: [l][lane][4]: (re[ln], re[64+ln], im[ln], im[64+ln])
#pragma unroll
    for (int t = hm; t < CL_ * 64; t += 128) {
        int i = t >> 6, ln = t & 63;
        ushort4 w;
        w.x = ct[i * CTS_ + ln];
        w.y = ct[i * CTS_ + 64 + ln];
        w.z = ct[i * CTS_ + 128 + ln];
        w.w = ct[i * CTS_ + 192 + ln];
        *(ushort4*)(ctb + (bkL + l0 + i) * 256 + ln * 4) = w;
    }
}

// chunk sums of vc
__global__ void ucs_kernel(const float* __restrict__ vc, float* __restrict__ ucs) {
    int idx = blockIdx.x * 256 + threadIdx.x;  // 64*128*32 = 262144
    int hout = idx & 31;
    int nc = (idx >> 5) & (NC_ - 1);
    int bk = idx >> 12;
    float s = 0.f;
#pragma unroll
    for (int j = 0; j < CL_; ++j)
        s += vc[(((size_t)bk * L_) + nc * CL_ + j) * 32 + hout];
    ucs[((size_t)bk * NC_ + nc) * 32 + hout] = s;
}

// exclusive scan of ucs over nc -> u_prev
__global__ void uscan_kernel(const float* __restrict__ ucs, float* __restrict__ u_prev) {
    int idx = blockIdx.x * 256 + threadIdx.x;  // 64*32 = 2048
    if (idx >= 64 * 32) return;
    int hout = idx & 31;
    int bk = idx >> 5;
    float run = 0.f;
#pragma unroll 8
    for (int nc = 0; nc < NC_; ++nc) {
        size_t o = ((size_t)bk * NC_ + nc) * 32 + hout;
        float v = ucs[o];
        u_prev[o] = run;
        run += v;
    }
}

// scan_fast: transcendental-free inner loop
__global__ __launch_bounds__(64) void scan_fast(const ushort* __restrict__ ctb,
                                                const float* __restrict__ pwb,
                                                const float* __restrict__ cs_re,
                                                const float* __restrict__ cs_im,
                                                const float* __restrict__ cs_den,
                                                const float* __restrict__ u_prev,
                                                const float* __restrict__ vc,
                                                const ushort* __restrict__ gateb,
                                                ushort* __restrict__ gq) {
    int nc = blockIdx.x, k = blockIdx.y, b = blockIdx.z;
    int lane = threadIdx.x;
    int bk = b * K_ + k;
    size_t bkL = (size_t)bk * L_;
    int hout = lane & 31;

    size_t o = ((size_t)(bk * NC_ + nc)) * 128;
    float are0 = cs_re[o + lane];
    float are1 = cs_re[o + 64 + lane];
    float aim0 = cs_im[o + lane];
    float aim1 = cs_im[o + 64 + lane];
    float den = cs_den[bk * NC_ + nc];
    float u = u_prev[((size_t)(bk * NC_ + nc)) * 32 + hout];
    int l0 = nc * CL_;

#pragma unroll 4
    for (int i = 0; i < CL_; ++i) {
        int l = l0 + i;
        ushort4 cb = *(const ushort4*)(ctb + (bkL + l) * 256 + lane * 4);
        float pw = pwb[bkL + l];
        are0 += b2f(cb.x); are1 += b2f(cb.y);
        aim0 += b2f(cb.z); aim1 += b2f(cb.w);
        den += pw;
        float s = are0 * are0 + are1 * are1 + aim0 * aim0 + aim1 * aim1;
#pragma unroll
        for (int off = 32; off; off >>= 1) s += __shfl_xor(s, off, 64);
        float inv = 1.f / fmaxf(den, 1e-4f);
        float rsq = rsqrtf(inv * inv * s * (1.0f / 256.0f) + 1e-5f);
        u += vc[(bkL + l) * 32 + hout];
        float gv = inv * rsq * u * b2f(gateb[(bkL + l) * 32 + hout]);
        if (lane < 32) gq[(size_t)(b * L_ + l) * D_ + k * H_ + hout] = f2bu(gv);
    }
}

// ============================ FALLBACK PATH (round-5, proven) ================

__global__ void conv_kernel(const float* __restrict__ z, const float* __restrict__ cw,
                            const float* __restrict__ cb, float* __restrict__ zck) {
    int t = blockIdx.x * 256 + threadIdx.x;
    if (t >= BL_ * (TOTAL_ / 4)) return;
    int c4 = (t % (TOTAL_ / 4)) * 4;
    int bl = t / (TOTAL_ / 4);
    int l = bl % L_, b = bl / L_;
    float4 acc = *(const float4*)(cb + c4);
#pragma unroll
    for (int tap = 0; tap < CK_; ++tap) {
        int ls = l - (CK_ - 1) + tap;
        if (ls >= 0) {
            float4 zv = *(const float4*)(z + (size_t)(bl - (CK_ - 1) + tap) * NPAD_ + c4);
            float4 wv = *(const float4*)(cw + tap * TOTAL_ + c4);
            acc.x = fmaf(zv.x, wv.x, acc.x);
            acc.y = fmaf(zv.y, wv.y, acc.y);
            acc.z = fmaf(zv.z, wv.z, acc.z);
            acc.w = fmaf(zv.w, wv.w, acc.w);
        }
    }
    if (c4 < D_) {
        int k = c4 >> 5, slot = c4 & 31;
        *(float4*)(zck + ((size_t)(b * K_ + k) * L_ + l) * ZS_ + slot) = acc;
    } else if (c4 < 2 * D_) {
        int cc = c4 - D_;
        int k = cc >> 5, slot = 32 + (cc & 31);
        *(float4*)(zck + ((size_t)(b * K_ + k) * L_ + l) * ZS_ + slot) = acc;
    } else if (c4 < 2 * D_ + K_) {
        float av[4] = {acc.x, acc.y, acc.z, acc.w};
#pragma unroll
        for (int q = 0; q < 4; ++q) {
            int k = c4 + q - 2 * D_;
            zck[((size_t)(b * K_ + k) * L_ + l) * ZS_ + 64] = av[q];
        }
    } else {
        int j = c4 - (2 * D_ + K_);
        int k = j >> 2;
        *(float4*)(zck + ((size_t)(b * K_ + k) * L_ + l) * ZS_ + 68) = acc;
    }
}

__global__ __launch_bounds__(128) void pass1(const float* __restrict__ zck,
                                             const float* __restrict__ mask,
                                             const float* __restrict__ theta_base,
                                             const float* __restrict__ trs_,
                                             const float* __restrict__ dslopes,
                                             const float* __restrict__ aslopes,
                                             const float* __restrict__ sscale_,
                                             const ushort* __restrict__ W2B,
                                             float* __restrict__ cs_re,
                                             float* __restrict__ cs_im,
                                             float* __restrict__ cs_den,
                                             float* __restrict__ vc) {
    __shared__ __align__(16) ushort ct[CL_ * CTS_];
    int nc = blockIdx.x, k = blockIdx.y, b = blockIdx.z;
    int hm = threadIdx.x;
    int h = hm >> 2, m = hm & 3;
    int bk = b * K_ + k;
    size_t bkL = (size_t)bk * L_;
    float raw = (k < DH_) ? dslopes[k] : aslopes[k - DH_];
    float slope = log1pf(__expf(raw));
    float sscale = sscale_[k];
    float trsv = trs_[k];
    float tb = theta_base[k * M_ + m];
    const float PI3 = 1.04719755119659775f;
    float are = 0.f, aim = 0.f, aden = 0.f;
    int l0 = nc * CL_;
#pragma unroll 4
    for (int i = 0; i < CL_; ++i) {
        int l = l0 + i;
        const float* zrow = zck + (bkL + l) * ZS_;
        float mval = mask[b * L_ + l];
        float s_raw = zrow[64] * mval;
        float tr = zrow[68 + m];
        float xv = zrow[h] * mval;
        float arg = fminf(fmaxf(sscale * s_raw, -20.f), 20.f);
        float p = __expf(arg) * mval;
        float tw = (k < DH_) ? __expf(-slope * (float)(L_ - 1 - l)) : __expf(-slope * (float)l);
        float pw = p * tw;
        float td = tr / (1.f + fabsf(tr));
        float theta = tb + trsv * (td * PI3);
        float phi = xv * theta;
        float sv = __sinf(phi), cv = __cosf(phi);
        unsigned short cu_re = f2bu(pw * cv);
        unsigned short cu_im = f2bu(pw * sv);
        are += b2f(cu_re); aim += b2f(cu_im); aden += pw;
        ct[i * CTS_ + hm] = cu_re;
        ct[i * CTS_ + 128 + hm] = cu_im;
    }
    size_t o = ((size_t)(bk * NC_ + nc)) * 128 + hm;
    cs_re[o] = are;
    cs_im[o] = aim;
    if (hm == 0) cs_den[bk * NC_ + nc] = aden;
    __syncthreads();
    int wave = hm >> 6, lane = hm & 63;
    int quad = lane >> 4, l16 = lane & 15;
    f32x4 acc = (f32x4){0.f, 0.f, 0.f, 0.f};
#pragma unroll
    for (int ks = 0; ks < 8; ++ks) {
        bf16x8 af = *(const bf16x8*)(ct + (size_t)l16 * CTS_ + ks * 32 + quad * 8);
        bf16x8 bfr = *(const bf16x8*)(W2B + (size_t)(wave * 16 + l16) * 256 + ks * 32 + quad * 8);
        acc = __builtin_amdgcn_mfma_f32_16x16x32_bf16(af, bfr, acc, 0, 0, 0);
    }
    size_t vbase = (bkL + l0) * 32;
#pragma unroll
    for (int r = 0; r < 4; ++r) {
        int row = quad * 4 + r;
        vc[vbase + (size_t)row * 32 + wave * 16 + l16] = acc[r];
    }
}

__global__ void pass2(float* cs_re, float* cs_im, float* cs_den) {
    int seq = blockIdx.x * 256 + threadIdx.x;
    if (seq >= B_ * K_ * 257) return;
    int bk = seq / 257;
    int ch = seq % 257;
    float* base;
    int stride;
    if (ch < 128) { base = cs_re + (size_t)bk * NC_ * 128 + ch; stride = 128; }
    else if (ch < 256) { base = cs_im + (size_t)bk * NC_ * 128 + (ch - 128); stride = 128; }
    else { base = cs_den + (size_t)bk * NC_; stride = 1; }
    float run = 0.f;
#pragma unroll 4
    for (int i = 0; i < NC_; ++i) {
        float v = base[(size_t)i * stride];
        base[(size_t)i * stride] = run;
        run += v;
    }
}

__global__ __launch_bounds__(64) void scan_kernel(const float* __restrict__ zck,
                                                  const float* __restrict__ mask,
                                                  const float* __restrict__ theta_base,
                                                  const float* __restrict__ trs_,
                                                  const float* __restrict__ dslopes,
                                                  const float* __restrict__ aslopes,
                                                  const float* __restrict__ sscale_,
                                                  const ushort* __restrict__ W2B,
                                                  const float* __restrict__ cs_re,
                                                  const float* __restrict__ cs_im,
                                                  const float* __restrict__ cs_den,
                                                  const float* __restrict__ vc,
                                                  ushort* __restrict__ gq) {
    int nc = blockIdx.x, k = blockIdx.y, b = blockIdx.z;
    int lane = threadIdx.x;
    int bk = b * K_ + k;
    size_t bkL = (size_t)bk * L_;
    int h0 = lane >> 2, h1 = 16 + (lane >> 2), m = lane & 3;
    int hout = lane & 31, half = lane >> 5;
    float raw = (k < DH_) ? dslopes[k] : aslopes[k - DH_];
    float slope = log1pf(__expf(raw));
    float sscale = sscale_[k];
    float trsv = trs_[k];
    float tb = theta_base[k * M_ + m];
    const float PI3 = 1.04719755119659775f;

    size_t o = ((size_t)(bk * NC_ + nc)) * 128;
    const float* srcp = half ? (cs_im + o) : (cs_re + o);
    float u = 0.f;
#pragma unroll 8
    for (int i = 0; i < 128; ++i)
        u = fmaf(srcp[i], b2f(W2B[hout * 256 + half * 128 + i]), u);
    u += __shfl_xor(u, 32, 64);

    float are0 = cs_re[o + lane];
    float are1 = cs_re[o + 64 + lane];
    float aim0 = cs_im[o + lane];
    float aim1 = cs_im[o + 64 + lane];
    float den = cs_den[bk * NC_ + nc];
    int l0 = nc * CL_;

#pragma unroll 4
    for (int i = 0; i < CL_; ++i) {
        int l = l0 + i;
        const float* zrow = zck + (bkL + l) * ZS_;
        float mval = mask[b * L_ + l];
        float s_raw = zrow[64] * mval;
        float tr = zrow[68 + m];
        float xv0 = zrow[h0] * mval;
        float xv1 = zrow[h1] * mval;
        float arg = fminf(fmaxf(sscale * s_raw, -20.f), 20.f);
        float p = __expf(arg) * mval;
        float tw = (k < DH_) ? __expf(-slope * (float)(L_ - 1 - l)) : __expf(-slope * (float)l);
        float pw = p * tw;
        float td = tr / (1.f + fabsf(tr));
        float theta = tb + trsv * (td * PI3);
        float s0 = __sinf(xv0 * theta), c0 = __cosf(xv0 * theta);
        float s1 = __sinf(xv1 * theta), c1 = __cosf(xv1 * theta);
        float cre0 = b2f(f2bu(pw * c0)), cim0 = b2f(f2bu(pw * s0));
        float cre1 = b2f(f2bu(pw * c1)), cim1 = b2f(f2bu(pw * s1));
        are0 += cre0; aim0 += cim0; are1 += cre1; aim1 += cim1;
        den += pw;
        float s = are0 * are0 + are1 * are1 + aim0 * aim0 + aim1 * aim1;
#pragma unroll
        for (int off = 32; off; off >>= 1) s += __shfl_xor(s, off, 64);
        float inv = 1.f / fmaxf(den, 1e-4f);
        float rsq = rsqrtf(inv * inv * s * (1.0f / 256.0f) + 1e-5f);
        float scv = inv * rsq;
        u += vc[(bkL + l) * 32 + hout];
        float y = scv * u;
        float zg = zrow[32 + hout];
        float gate = zg / (1.f + __expf(-zg));
        if (lane < 32) gq[(size_t)(b * L_ + l) * D_ + k * H_ + hout] = f2bu(y * gate);
    }
}

extern "C" void kernel_launch(void* const* d_in, const int* in_sizes, int n_in,
                              void* d_out, int out_size, void* d_ws, size_t ws_size,
                              hipStream_t stream) {
    const float* x = (const float*)d_in[0];
    const float* mask = (const float*)d_in[1];
    const float* W_in = (const float*)d_in[2];
    const float* conv_w = (const float*)d_in[3];
    const float* conv_b = (const float*)d_in[4];
    const float* theta_base = (const float*)d_in[5];
    const float* trs = (const float*)d_in[6];
    const float* dsl = (const float*)d_in[7];
    const float* asl = (const float*)d_in[8];
    const float* ssc = (const float*)d_in[9];
    const float* nsc = (const float*)d_in[10];
    const float* Wre = (const float*)d_in[11];
    const float* Wim = (const float*)d_in[12];
    const float* Wout = (const float*)d_in[13];
    float* out = (float*)d_out;

    char* ws = (char*)d_ws;
    const size_t NEED_FAST = 115359744ULL;

    if (ws_size >= NEED_FAST) {
        // ---- fast path layout ----
        float* zck2   = (float*)(ws);                    // 67,108,864 (ctb in-place)
        ushort* ctb   = (ushort*)(ws);
        ushort* x_bf  = (ushort*)(ws);                   // [0, 8.4M) dead before conv
        ushort* Wt_in = (ushort*)(ws + 8388608ULL);      // dead before conv
        ushort* gateb = (ushort*)(ws + 67108864ULL);     // 8,388,608
        float* z      = (float*)(ws + 75497472ULL);      // 37,748,736 (dead after conv)
        float* vc     = (float*)(ws + 75497472ULL);      // 16,777,216
        float* cs_re  = (float*)(ws + 92274688ULL);      // 4,194,304
        float* cs_im  = (float*)(ws + 96468992ULL);      // 4,194,304
        float* cs_den = (float*)(ws + 100663296ULL);     // 32,768
        float* pwb    = (float*)(ws + 100696064ULL);     // 524,288
        float* u_prev = (float*)(ws + 101220352ULL);     // 1,048,576
        float* ucs    = (float*)(ws + 102268928ULL);     // 1,048,576
        ushort* gq    = (ushort*)(ws + 103317504ULL);    // 8,388,608 (ends 111,706,112)
        ushort* Wt_o  = (ushort*)(ws + 113246208ULL);    // 2,097,152
        ushort* W2B   = (ushort*)(ws + 115343360ULL);    // 16,384

        convert_x<<<4096, 256, 0, stream>>>((const float4*)x, x_bf);
        transpose_bf16_pad<<<dim3(NPAD_ / 64, 16), 256, 0, stream>>>(W_in, Wt_in, 1024, TOTAL_);
        transpose_bf16_pad<<<dim3(16, 16), 256, 0, stream>>>(Wout, Wt_o, 1024, 1024);
        prep_w2<<<1, 256, 0, stream>>>(Wre, Wim, nsc, W2B);
        gemm_bt<<<dim3(NPAD_ / 128, BL_ / 128), 256, 0, stream>>>(x_bf, Wt_in, z, 1024, NPAD_);
        conv_fast<<<(BL_ * (TOTAL_ / 4) + 255) / 256, 256, 0, stream>>>(z, conv_w, conv_b, zck2, gateb);
        pass1_fast<<<dim3(NC_, K_, B_), 128, 0, stream>>>(zck2, mask, theta_base, trs, dsl, asl,
                                                          ssc, W2B, cs_re, cs_im, cs_den, vc, ctb, pwb);
        pass2<<<(B_ * K_ * 257 + 255) / 256, 256, 0, stream>>>(cs_re, cs_im, cs_den);
        ucs_kernel<<<1024, 256, 0, stream>>>(vc, ucs);
        uscan_kernel<<<8, 256, 0, stream>>>(ucs, u_prev);
        scan_fast<<<dim3(NC_, K_, B_), 64, 0, stream>>>(ctb, pwb, cs_re, cs_im, cs_den,
                                                        u_prev, vc, gateb, gq);
        gemm_bt<<<dim3(D_ / 128, BL_ / 128), 256, 0, stream>>>(gq, Wt_o, out, 1024, 1024);
    } else {
        // ---- fallback: round-5 proven path ----
        float* zck    = (float*)(ws);
        float* z      = (float*)(ws + 37748736ULL);
        float* cs_re  = (float*)(ws + 37748736ULL);
        float* cs_im  = (float*)(ws + 41943040ULL);
        float* cs_den = (float*)(ws + 46137344ULL);
        ushort* gq    = (ushort*)(ws + 46170112ULL);
        ushort* x_bf  = (ushort*)(ws + 75497472ULL);
        ushort* Wt_in = (ushort*)(ws + 83886080ULL);
        float* vc     = (float*)(ws + 75497472ULL);
        ushort* Wt_o  = (ushort*)(ws + 92274688ULL);
        ushort* W2B   = (ushort*)(ws + 94371840ULL);

        convert_x<<<4096, 256, 0, stream>>>((const float4*)x, x_bf);
        transpose_bf16_pad<<<dim3(NPAD_ / 64, 16), 256, 0, stream>>>(W_in, Wt_in, 1024, TOTAL_);
        transpose_bf16_pad<<<dim3(16, 16), 256, 0, stream>>>(Wout, Wt_o, 1024, 1024);
        prep_w2<<<1, 256, 0, stream>>>(Wre, Wim, nsc, W2B);
        gemm_bt<<<dim3(NPAD_ / 128, BL_ / 128), 256, 0, stream>>>(x_bf, Wt_in, z, 1024, NPAD_);
        conv_kernel<<<(BL_ * (TOTAL_ / 4) + 255) / 256, 256, 0, stream>>>(z, conv_w, conv_b, zck);
        pass1<<<dim3(NC_, K_, B_), 128, 0, stream>>>(zck, mask, theta_base, trs, dsl, asl, ssc,
                                                     W2B, cs_re, cs_im, cs_den, vc);
        pass2<<<(B_ * K_ * 257 + 255) / 256, 256, 0, stream>>>(cs_re, cs_im, cs_den);
        scan_kernel<<<dim3(NC_, K_, B_), 64, 0, stream>>>(zck, mask, theta_base, trs, dsl, asl, ssc,
                                                          W2B, cs_re, cs_im, cs_den, vc, gq);
        gemm_bt<<<dim3(D_ / 128, BL_ / 128), 256, 0, stream>>>(gq, Wt_o, out, 1024, 1024);
    }
}

// Round 7
// 260.049 us; speedup vs baseline: 1.1695x; 1.1579x over previous
//
#include <hip/hip_runtime.h>
#include <hip/hip_bf16.h>
#include <math.h>

#define B_ 2
#define L_ 2048
#define D_ 1024
#define K_ 32
#define M_ 4
#define H_ 32
#define AH_ 4
#define DH_ 28
#define CK_ 4
#define TOTAL_ 2208
#define NPAD_ 2304
#define BL_ (B_*L_)
#define CL_ 16
#define NC_ (L_/CL_)   // 128
#define CTS_ 280       // ct row stride (ushorts)

typedef __attribute__((ext_vector_type(8))) short bf16x8;
typedef __attribute__((ext_vector_type(4))) float f32x4;

static __device__ inline unsigned short f2bu(float f) {
    union { __hip_bfloat16 h; unsigned short u; } cv;
    cv.h = __float2bfloat16(f);
    return cv.u;
}
static __device__ inline float b2f(unsigned short u) {
    union { unsigned short u; __hip_bfloat16 h; } cv;
    cv.u = u;
    return __bfloat162float(cv.h);
}
// identical FMA chain in pass1f and scan_k7 so recomputed values match bitwise
static __device__ inline float conv4(float bias, const float w[4], float r0, float r1,
                                     float r2, float zc) {
    return fmaf(w[3], zc, fmaf(w[2], r2, fmaf(w[1], r1, fmaf(w[0], r0, bias))));
}

// ---------- fused prep: x->bf16, W_in^T, Wout^T, W2B (one launch) ----------
__global__ __launch_bounds__(256) void prep_all(const float* __restrict__ x,
                                                const float* __restrict__ W_in,
                                                const float* __restrict__ Wout,
                                                const float* __restrict__ Wre,
                                                const float* __restrict__ Wim,
                                                const float* __restrict__ nscale,
                                                ushort* __restrict__ x_bf,
                                                ushort* __restrict__ Wt_in,
                                                ushort* __restrict__ Wt_o,
                                                ushort* __restrict__ W2B) {
    __shared__ float tile[64][65];
    int bid = blockIdx.x, t = threadIdx.x;
    if (bid < 4096) {
        int i = bid * 256 + t;
        float4 v = ((const float4*)x)[i];
        ushort4 o;
        o.x = f2bu(v.x); o.y = f2bu(v.y); o.z = f2bu(v.z); o.w = f2bu(v.w);
        *(ushort4*)(x_bf + (size_t)i * 4) = o;
        return;
    }
    const float* src; ushort* dst; int Kd, N, n0, k0;
    if (bid < 4096 + 576) {
        int bb = bid - 4096;
        src = W_in; dst = Wt_in; Kd = 1024; N = TOTAL_;
        n0 = (bb % 36) * 64; k0 = (bb / 36) * 64;
    } else if (bid < 4096 + 576 + 256) {
        int bb = bid - 4096 - 576;
        src = Wout; dst = Wt_o; Kd = 1024; N = 1024;
        n0 = (bb % 16) * 64; k0 = (bb / 16) * 64;
    } else {
        int ch = t;  // 256
        float ns = nscale[ch];
        for (int ho = 0; ho < 32; ++ho) {
            float w = (ch < 128) ? Wre[ch * 32 + ho] : Wim[(ch - 128) * 32 + ho];
            W2B[ho * 256 + ch] = f2bu(ns * w);
        }
        return;
    }
#pragma unroll
    for (int i = 0; i < 16; ++i) {
        int idx = t + i * 256;
        int r = idx >> 6, c = idx & 63;
        int gn = n0 + c;
        tile[r][c] = (gn < N) ? src[(size_t)(k0 + r) * N + gn] : 0.f;
    }
    __syncthreads();
#pragma unroll
    for (int i = 0; i < 16; ++i) {
        int idx = t + i * 256;
        int r = idx >> 6, c = idx & 63;
        dst[(size_t)(n0 + r) * Kd + k0 + c] = f2bu(tile[c][r]);
    }
}

// ---------- bf16 MFMA GEMM: C[M,N] = A[M,Kd] @ Bt[N,Kd]^T ----------
__global__ __launch_bounds__(256) void gemm_bt(const ushort* __restrict__ A,
                                               const ushort* __restrict__ Bt,
                                               float* __restrict__ C,
                                               int Kd, int ldc) {
    __shared__ __align__(16) ushort As[128 * 32];
    __shared__ __align__(16) ushort Bs[128 * 32];
    int tid = threadIdx.x;
    int wave = tid >> 6, lane = tid & 63;
    int quad = lane >> 4, l16 = lane & 15;
    int m0 = blockIdx.y * 128, n0 = blockIdx.x * 128;
    int wm = (wave >> 1) * 64, wn = (wave & 1) * 64;
    f32x4 acc[4][4];
#pragma unroll
    for (int i = 0; i < 4; ++i)
#pragma unroll
        for (int j = 0; j < 4; ++j) acc[i][j] = (f32x4){0.f, 0.f, 0.f, 0.f};

    int swzq = quad ^ (l16 & 3);

    for (int k0 = 0; k0 < Kd; k0 += 32) {
#pragma unroll
        for (int i = 0; i < 2; ++i) {
            int s = i * 256 + tid;
            int row = s >> 2;
            int qg = (s & 3) ^ (row & 3);
            const ushort* ga = A + (size_t)(m0 + row) * Kd + k0 + qg * 8;
            const ushort* gb = Bt + (size_t)(n0 + row) * Kd + k0 + qg * 8;
            __builtin_amdgcn_global_load_lds((const __attribute__((address_space(1))) void*)ga,
                                             (__attribute__((address_space(3))) void*)(As + (size_t)s * 8),
                                             16, 0, 0);
            __builtin_amdgcn_global_load_lds((const __attribute__((address_space(1))) void*)gb,
                                             (__attribute__((address_space(3))) void*)(Bs + (size_t)s * 8),
                                             16, 0, 0);
        }
        __syncthreads();
        bf16x8 af[4], bfr[4];
#pragma unroll
        for (int mi = 0; mi < 4; ++mi)
            af[mi] = *(const bf16x8*)(As + (size_t)(wm + mi * 16 + l16) * 32 + swzq * 8);
#pragma unroll
        for (int ni = 0; ni < 4; ++ni)
            bfr[ni] = *(const bf16x8*)(Bs + (size_t)(wn + ni * 16 + l16) * 32 + swzq * 8);
#pragma unroll
        for (int mi = 0; mi < 4; ++mi)
#pragma unroll
            for (int ni = 0; ni < 4; ++ni)
                acc[mi][ni] = __builtin_amdgcn_mfma_f32_16x16x32_bf16(af[mi], bfr[ni], acc[mi][ni], 0, 0, 0);
        __syncthreads();
    }
#pragma unroll
    for (int mi = 0; mi < 4; ++mi)
#pragma unroll
        for (int ni = 0; ni < 4; ++ni)
#pragma unroll
            for (int r = 0; r < 4; ++r) {
                int gm = m0 + wm + mi * 16 + quad * 4 + r;
                int gn = n0 + wn + ni * 16 + l16;
                C[(size_t)gm * ldc + gn] = acc[mi][ni][r];
            }
}

// ---------- pass1f: fused conv (reg ring) + chunk sums + vc MFMA + ucs -------
__global__ __launch_bounds__(128) void pass1f(const float* __restrict__ z,
                                              const float* __restrict__ mask,
                                              const float* __restrict__ theta_base,
                                              const float* __restrict__ trs_,
                                              const float* __restrict__ dslopes,
                                              const float* __restrict__ aslopes,
                                              const float* __restrict__ sscale_,
                                              const float* __restrict__ conv_w,
                                              const float* __restrict__ conv_b,
                                              const ushort* __restrict__ W2B,
                                              float* __restrict__ cs_re,
                                              float* __restrict__ cs_im,
                                              float* __restrict__ cs_den,
                                              float* __restrict__ vc,
                                              float* __restrict__ ucs) {
    __shared__ __align__(16) ushort ct[CL_ * CTS_];
    int nc = blockIdx.x, k = blockIdx.y, b = blockIdx.z;
    int hm = threadIdx.x;
    int h = hm >> 2, m = hm & 3;
    int bk = b * K_ + k;
    size_t bkL = (size_t)bk * L_;
    int cxv = k * H_ + h, csc = 2 * D_ + k, cth = 2 * D_ + K_ + k * M_ + m;
    float wx[4], ws4[4], wt4[4];
#pragma unroll
    for (int t = 0; t < 4; ++t) {
        wx[t] = conv_w[t * TOTAL_ + cxv];
        ws4[t] = conv_w[t * TOTAL_ + csc];
        wt4[t] = conv_w[t * TOTAL_ + cth];
    }
    float bx = conv_b[cxv], bs = conv_b[csc], bt = conv_b[cth];
    int l0 = nc * CL_;
    float rx[3], rs[3], rt[3];
#pragma unroll
    for (int j = 0; j < 3; ++j) {
        int ls = l0 - 3 + j;
        if (ls >= 0) {
            size_t zo = (size_t)(b * L_ + ls) * NPAD_;
            rx[j] = z[zo + cxv]; rs[j] = z[zo + csc]; rt[j] = z[zo + cth];
        } else { rx[j] = 0.f; rs[j] = 0.f; rt[j] = 0.f; }
    }
    float raw = (k < DH_) ? dslopes[k] : aslopes[k - DH_];
    float slope = log1pf(__expf(raw));
    float sscale = sscale_[k], trsv = trs_[k], tb = theta_base[k * M_ + m];
    const float PI3 = 1.04719755119659775f;
    float tw = (k < DH_) ? __expf(-slope * (float)(L_ - 1 - l0)) : __expf(-slope * (float)l0);
    float e_s = (k < DH_) ? __expf(slope) : __expf(-slope);
    float are = 0.f, aim = 0.f, aden = 0.f;
#pragma unroll 4
    for (int i = 0; i < CL_; ++i) {
        int l = l0 + i;
        int row = b * L_ + l;
        size_t zo = (size_t)row * NPAD_;
        float zx = z[zo + cxv], zs = z[zo + csc], zt = z[zo + cth];
        float mval = mask[row];
        float xv = conv4(bx, wx, rx[0], rx[1], rx[2], zx) * mval;
        float s_raw = conv4(bs, ws4, rs[0], rs[1], rs[2], zs) * mval;
        float tr = conv4(bt, wt4, rt[0], rt[1], rt[2], zt);
        rx[0] = rx[1]; rx[1] = rx[2]; rx[2] = zx;
        rs[0] = rs[1]; rs[1] = rs[2]; rs[2] = zs;
        rt[0] = rt[1]; rt[1] = rt[2]; rt[2] = zt;
        float arg = fminf(fmaxf(sscale * s_raw, -20.f), 20.f);
        float p = __expf(arg) * mval;
        float pw = p * tw;
        tw *= e_s;
        float td = tr / (1.f + fabsf(tr));
        float theta = tb + trsv * (td * PI3);
        float phi = xv * theta;
        float sv = __sinf(phi), cv = __cosf(phi);
        unsigned short cu_re = f2bu(pw * cv);
        unsigned short cu_im = f2bu(pw * sv);
        are += b2f(cu_re); aim += b2f(cu_im); aden += pw;
        ct[i * CTS_ + hm] = cu_re;
        ct[i * CTS_ + 128 + hm] = cu_im;
    }
    size_t o = ((size_t)(bk * NC_ + nc)) * 128 + hm;
    cs_re[o] = are;
    cs_im[o] = aim;
    if (hm == 0) cs_den[bk * NC_ + nc] = aden;
    __syncthreads();
    // vc = C_chunk(16x256) @ W''(256x32); wave w -> hout tile w
    int wave = hm >> 6, lane = hm & 63;
    int quad = lane >> 4, l16 = lane & 15;
    f32x4 acc = (f32x4){0.f, 0.f, 0.f, 0.f};
#pragma unroll
    for (int ks = 0; ks < 8; ++ks) {
        bf16x8 af = *(const bf16x8*)(ct + (size_t)l16 * CTS_ + ks * 32 + quad * 8);
        bf16x8 bfr = *(const bf16x8*)(W2B + (size_t)(wave * 16 + l16) * 256 + ks * 32 + quad * 8);
        acc = __builtin_amdgcn_mfma_f32_16x16x32_bf16(af, bfr, acc, 0, 0, 0);
    }
    size_t vbase = (bkL + l0) * 32;
#pragma unroll
    for (int r = 0; r < 4; ++r) {
        int rowv = quad * 4 + r;
        vc[vbase + (size_t)rowv * 32 + wave * 16 + l16] = acc[r];
    }
    // ucs[bk][nc][hout] = sum of this chunk's vc rows (for the u-prefix scan)
    float part = acc[0] + acc[1] + acc[2] + acc[3];
    part += __shfl_xor(part, 16, 64);
    part += __shfl_xor(part, 32, 64);
    if (quad == 0) ucs[((size_t)(bk * NC_ + nc)) * 32 + wave * 16 + l16] = part;
}

// ---------- scan2: fused pass2 (cs exclusive scan) + u_prev scan -------------
__global__ void scan2(float* cs_re, float* cs_im, float* cs_den,
                      const float* __restrict__ ucs, float* __restrict__ u_prev) {
    int bid = blockIdx.x, tid = threadIdx.x;
    if (bid < 65) {
        int seq = bid * 256 + tid;
        if (seq >= B_ * K_ * 257) return;
        int bk = seq / 257;
        int ch = seq % 257;
        float* base;
        int stride;
        if (ch < 128) { base = cs_re + (size_t)bk * NC_ * 128 + ch; stride = 128; }
        else if (ch < 256) { base = cs_im + (size_t)bk * NC_ * 128 + (ch - 128); stride = 128; }
        else { base = cs_den + (size_t)bk * NC_; stride = 1; }
        float run = 0.f;
#pragma unroll 4
        for (int i = 0; i < NC_; ++i) {
            float v = base[(size_t)i * stride];
            base[(size_t)i * stride] = run;
            run += v;
        }
    } else {
        int idx = (bid - 65) * 256 + tid;  // 0..2047
        int hout = idx & 31;
        int bk = idx >> 5;
        float run = 0.f;
#pragma unroll 8
        for (int nc = 0; nc < NC_; ++nc) {
            size_t o = ((size_t)bk * NC_ + nc) * 32 + hout;
            float v = ucs[o];
            u_prev[o] = run;
            run += v;
        }
    }
}

// ---------- scan_k7: fused conv + barrier-free scan + norm + gate + store ----
__global__ __launch_bounds__(64) void scan_k7(const float* __restrict__ z,
                                              const float* __restrict__ mask,
                                              const float* __restrict__ theta_base,
                                              const float* __restrict__ trs_,
                                              const float* __restrict__ dslopes,
                                              const float* __restrict__ aslopes,
                                              const float* __restrict__ sscale_,
                                              const float* __restrict__ conv_w,
                                              const float* __restrict__ conv_b,
                                              const float* __restrict__ cs_re,
                                              const float* __restrict__ cs_im,
                                              const float* __restrict__ cs_den,
                                              const float* __restrict__ u_prev,
                                              const float* __restrict__ vc,
                                              ushort* __restrict__ gq) {
    int nc = blockIdx.x, k = blockIdx.y, b = blockIdx.z;
    int lane = threadIdx.x;
    int bk = b * K_ + k;
    size_t bkL = (size_t)bk * L_;
    int h0 = lane >> 2, m = lane & 3;
    int hout = lane & 31;
    int c0 = k * H_ + h0, c1 = k * H_ + 16 + h0;
    int csc = 2 * D_ + k, cth = 2 * D_ + K_ + k * M_ + m, cg = D_ + k * H_ + hout;
    float w0[4], w1[4], ws4[4], wt4[4], wg[4];
#pragma unroll
    for (int t = 0; t < 4; ++t) {
        w0[t] = conv_w[t * TOTAL_ + c0];
        w1[t] = conv_w[t * TOTAL_ + c1];
        ws4[t] = conv_w[t * TOTAL_ + csc];
        wt4[t] = conv_w[t * TOTAL_ + cth];
        wg[t] = conv_w[t * TOTAL_ + cg];
    }
    float b0c = conv_b[c0], b1c = conv_b[c1], bsc = conv_b[csc], btc = conv_b[cth], bgc = conv_b[cg];
    int l0 = nc * CL_;
    float r0[3], r1[3], rs[3], rt[3], rg[3];
#pragma unroll
    for (int j = 0; j < 3; ++j) {
        int ls = l0 - 3 + j;
        if (ls >= 0) {
            size_t zo = (size_t)(b * L_ + ls) * NPAD_;
            r0[j] = z[zo + c0]; r1[j] = z[zo + c1]; rs[j] = z[zo + csc];
            rt[j] = z[zo + cth]; rg[j] = z[zo + cg];
        } else { r0[j] = 0.f; r1[j] = 0.f; rs[j] = 0.f; rt[j] = 0.f; rg[j] = 0.f; }
    }
    float raw = (k < DH_) ? dslopes[k] : aslopes[k - DH_];
    float slope = log1pf(__expf(raw));
    float sscale = sscale_[k], trsv = trs_[k], tb = theta_base[k * M_ + m];
    const float PI3 = 1.04719755119659775f;
    float tw = (k < DH_) ? __expf(-slope * (float)(L_ - 1 - l0)) : __expf(-slope * (float)l0);
    float e_s = (k < DH_) ? __expf(slope) : __expf(-slope);

    size_t o = ((size_t)(bk * NC_ + nc)) * 128;
    float are0 = cs_re[o + lane];
    float are1 = cs_re[o + 64 + lane];
    float aim0 = cs_im[o + lane];
    float aim1 = cs_im[o + 64 + lane];
    float den = cs_den[bk * NC_ + nc];
    float u = u_prev[((size_t)(bk * NC_ + nc)) * 32 + hout];

#pragma unroll 4
    for (int i = 0; i < CL_; ++i) {
        int l = l0 + i;
        int row = b * L_ + l;
        size_t zo = (size_t)row * NPAD_;
        float z0 = z[zo + c0], z1 = z[zo + c1], zs = z[zo + csc];
        float zt = z[zo + cth], zg = z[zo + cg];
        float mval = mask[row];
        float xv0 = conv4(b0c, w0, r0[0], r0[1], r0[2], z0) * mval;
        float xv1 = conv4(b1c, w1, r1[0], r1[1], r1[2], z1) * mval;
        float s_raw = conv4(bsc, ws4, rs[0], rs[1], rs[2], zs) * mval;
        float tr = conv4(btc, wt4, rt[0], rt[1], rt[2], zt);
        float gpre = conv4(bgc, wg, rg[0], rg[1], rg[2], zg);
        r0[0] = r0[1]; r0[1] = r0[2]; r0[2] = z0;
        r1[0] = r1[1]; r1[1] = r1[2]; r1[2] = z1;
        rs[0] = rs[1]; rs[1] = rs[2]; rs[2] = zs;
        rt[0] = rt[1]; rt[1] = rt[2]; rt[2] = zt;
        rg[0] = rg[1]; rg[1] = rg[2]; rg[2] = zg;
        float arg = fminf(fmaxf(sscale * s_raw, -20.f), 20.f);
        float p = __expf(arg) * mval;
        float pw = p * tw;
        tw *= e_s;
        float td = tr / (1.f + fabsf(tr));
        float theta = tb + trsv * (td * PI3);
        float s0 = __sinf(xv0 * theta), cv0 = __cosf(xv0 * theta);
        float s1 = __sinf(xv1 * theta), cv1 = __cosf(xv1 * theta);
        // bf16-round to match pass1f's sums exactly
        float cre0 = b2f(f2bu(pw * cv0)), cim0 = b2f(f2bu(pw * s0));
        float cre1 = b2f(f2bu(pw * cv1)), cim1 = b2f(f2bu(pw * s1));
        are0 += cre0; aim0 += cim0; are1 += cre1; aim1 += cim1;
        den += pw;
        float s = are0 * are0 + are1 * are1 + aim0 * aim0 + aim1 * aim1;
#pragma unroll
        for (int off = 32; off; off >>= 1) s += __shfl_xor(s, off, 64);
        float inv = 1.f / fmaxf(den, 1e-4f);
        float rsq = rsqrtf(inv * inv * s * (1.0f / 256.0f) + 1e-5f);
        float scv = inv * rsq;
        u += vc[(bkL + l) * 32 + hout];
        float y = scv * u;
        float gate = gpre / (1.f + __expf(-gpre));
        if (lane < 32) gq[(size_t)row * D_ + k * H_ + hout] = f2bu(y * gate);
    }
}

extern "C" void kernel_launch(void* const* d_in, const int* in_sizes, int n_in,
                              void* d_out, int out_size, void* d_ws, size_t ws_size,
                              hipStream_t stream) {
    const float* x = (const float*)d_in[0];
    const float* mask = (const float*)d_in[1];
    const float* W_in = (const float*)d_in[2];
    const float* conv_w = (const float*)d_in[3];
    const float* conv_b = (const float*)d_in[4];
    const float* theta_base = (const float*)d_in[5];
    const float* trs = (const float*)d_in[6];
    const float* dsl = (const float*)d_in[7];
    const float* asl = (const float*)d_in[8];
    const float* ssc = (const float*)d_in[9];
    const float* nsc = (const float*)d_in[10];
    const float* Wre = (const float*)d_in[11];
    const float* Wim = (const float*)d_in[12];
    const float* Wout = (const float*)d_in[13];
    float* out = (float*)d_out;

    char* ws = (char*)d_ws;
    float* z      = (float*)(ws);                    // 37,748,736
    ushort* x_bf  = (ushort*)(ws + 37748736ULL);     // 8,388,608
    ushort* Wt_in = (ushort*)(ws + 46137344ULL);     // 4,718,592
    ushort* Wt_o  = (ushort*)(ws + 50855936ULL);     // 2,097,152
    ushort* W2B   = (ushort*)(ws + 52953088ULL);     // 16,384
    float* vc     = (float*)(ws + 52969472ULL);      // 16,777,216
    float* cs_re  = (float*)(ws + 69746688ULL);      // 4,194,304
    float* cs_im  = (float*)(ws + 73940992ULL);      // 4,194,304
    float* cs_den = (float*)(ws + 78135296ULL);      // 32,768
    float* ucs    = (float*)(ws + 78168064ULL);      // 1,048,576
    float* u_prev = (float*)(ws + 79216640ULL);      // 1,048,576
    ushort* gq    = (ushort*)(ws + 80265216ULL);     // 8,388,608 (ends 88,653,824)

    prep_all<<<4096 + 576 + 256 + 1, 256, 0, stream>>>(x, W_in, Wout, Wre, Wim, nsc,
                                                       x_bf, Wt_in, Wt_o, W2B);
    gemm_bt<<<dim3(NPAD_ / 128, BL_ / 128), 256, 0, stream>>>(x_bf, Wt_in, z, 1024, NPAD_);
    pass1f<<<dim3(NC_, K_, B_), 128, 0, stream>>>(z, mask, theta_base, trs, dsl, asl, ssc,
                                                  conv_w, conv_b, W2B,
                                                  cs_re, cs_im, cs_den, vc, ucs);
    scan2<<<73, 256, 0, stream>>>(cs_re, cs_im, cs_den, ucs, u_prev);
    scan_k7<<<dim3(NC_, K_, B_), 64, 0, stream>>>(z, mask, theta_base, trs, dsl, asl, ssc,
                                                  conv_w, conv_b, cs_re, cs_im, cs_den,
                                                  u_prev, vc, gq);
    gemm_bt<<<dim3(D_ / 128, BL_ / 128), 256, 0, stream>>>(gq, Wt_o, out, 1024, 1024);
}

// Round 8
// 256.896 us; speedup vs baseline: 1.1839x; 1.0123x over previous
//
#include <hip/hip_runtime.h>
#include <hip/hip_bf16.h>
#include <math.h>

#define B_ 2
#define L_ 2048
#define D_ 1024
#define K_ 32
#define M_ 4
#define H_ 32
#define AH_ 4
#define DH_ 28
#define CK_ 4
#define TOTAL_ 2208
#define NPAD_ 2304
#define BL_ (B_*L_)
#define CL_ 16
#define NC_ (L_/CL_)   // 128
#define CTS_ 280       // ct row stride (ushorts)

typedef __attribute__((ext_vector_type(8))) short bf16x8;
typedef __attribute__((ext_vector_type(4))) float f32x4;

static __device__ inline unsigned short f2bu(float f) {
    union { __hip_bfloat16 h; unsigned short u; } cv;
    cv.h = __float2bfloat16(f);
    return cv.u;
}
static __device__ inline float b2f(unsigned short u) {
    union { unsigned short u; __hip_bfloat16 h; } cv;
    cv.u = u;
    return __bfloat162float(cv.h);
}
// identical FMA chain in pass1f and scan_k7 so recomputed values match bitwise
static __device__ inline float conv4(float bias, const float w[4], float r0, float r1,
                                     float r2, float zc) {
    return fmaf(w[3], zc, fmaf(w[2], r2, fmaf(w[1], r1, fmaf(w[0], r0, bias))));
}

// ---------- fused prep: x->bf16, W_in^T, Wout^T, W2B (one launch) ----------
__global__ __launch_bounds__(256) void prep_all(const float* __restrict__ x,
                                                const float* __restrict__ W_in,
                                                const float* __restrict__ Wout,
                                                const float* __restrict__ Wre,
                                                const float* __restrict__ Wim,
                                                const float* __restrict__ nscale,
                                                ushort* __restrict__ x_bf,
                                                ushort* __restrict__ Wt_in,
                                                ushort* __restrict__ Wt_o,
                                                ushort* __restrict__ W2B) {
    __shared__ float tile[64][65];
    int bid = blockIdx.x, t = threadIdx.x;
    if (bid < 4096) {
        int i = bid * 256 + t;
        float4 v = ((const float4*)x)[i];
        ushort4 o;
        o.x = f2bu(v.x); o.y = f2bu(v.y); o.z = f2bu(v.z); o.w = f2bu(v.w);
        *(ushort4*)(x_bf + (size_t)i * 4) = o;
        return;
    }
    const float* src; ushort* dst; int Kd, N, n0, k0;
    if (bid < 4096 + 576) {
        int bb = bid - 4096;
        src = W_in; dst = Wt_in; Kd = 1024; N = TOTAL_;
        n0 = (bb % 36) * 64; k0 = (bb / 36) * 64;
    } else if (bid < 4096 + 576 + 256) {
        int bb = bid - 4096 - 576;
        src = Wout; dst = Wt_o; Kd = 1024; N = 1024;
        n0 = (bb % 16) * 64; k0 = (bb / 16) * 64;
    } else {
        int ch = t;  // 256
        float ns = nscale[ch];
        for (int ho = 0; ho < 32; ++ho) {
            float w = (ch < 128) ? Wre[ch * 32 + ho] : Wim[(ch - 128) * 32 + ho];
            W2B[ho * 256 + ch] = f2bu(ns * w);
        }
        return;
    }
#pragma unroll
    for (int i = 0; i < 16; ++i) {
        int idx = t + i * 256;
        int r = idx >> 6, c = idx & 63;
        int gn = n0 + c;
        tile[r][c] = (gn < N) ? src[(size_t)(k0 + r) * N + gn] : 0.f;
    }
    __syncthreads();
#pragma unroll
    for (int i = 0; i < 16; ++i) {
        int idx = t + i * 256;
        int r = idx >> 6, c = idx & 63;
        dst[(size_t)(n0 + r) * Kd + k0 + c] = f2bu(tile[c][r]);
    }
}

// ---------- bf16 MFMA GEMM, 64(M)x128(N) tile, 4 waves of 32x64 --------------
// Whole grid co-resident (4.5 blocks/CU at 1152 blocks) -> no tail round.
template <bool OUT_BF16>
__global__ __launch_bounds__(256) void gemm_bt64(const ushort* __restrict__ A,
                                                 const ushort* __restrict__ Bt,
                                                 void* __restrict__ Cv,
                                                 int Kd, int ldc) {
    __shared__ __align__(16) ushort SB[192 * 32];   // rows 0-63: A, 64-191: Bt
    int tid = threadIdx.x;
    int wave = tid >> 6, lane = tid & 63;
    int quad = lane >> 4, l16 = lane & 15;
    int n0 = blockIdx.x * 128, m0 = blockIdx.y * 64;
    int wm = (wave & 1) * 32, wn = (wave >> 1) * 64;
    f32x4 acc[2][4];
#pragma unroll
    for (int i = 0; i < 2; ++i)
#pragma unroll
        for (int j = 0; j < 4; ++j) acc[i][j] = (f32x4){0.f, 0.f, 0.f, 0.f};

    int swzq = quad ^ (l16 & 3);

    for (int k0 = 0; k0 < Kd; k0 += 32) {
#pragma unroll
        for (int i = 0; i < 3; ++i) {
            int s = i * 256 + tid;            // 768 16B-slots
            int row = s >> 2;
            int qg = (s & 3) ^ (row & 3);
            const ushort* g = (row < 64) ? A + (size_t)(m0 + row) * Kd + k0 + qg * 8
                                         : Bt + (size_t)(n0 + row - 64) * Kd + k0 + qg * 8;
            __builtin_amdgcn_global_load_lds((const __attribute__((address_space(1))) void*)g,
                                             (__attribute__((address_space(3))) void*)(SB + (size_t)s * 8),
                                             16, 0, 0);
        }
        __syncthreads();
        bf16x8 af[2], bfr[4];
#pragma unroll
        for (int mi = 0; mi < 2; ++mi)
            af[mi] = *(const bf16x8*)(SB + (size_t)(wm + mi * 16 + l16) * 32 + swzq * 8);
#pragma unroll
        for (int ni = 0; ni < 4; ++ni)
            bfr[ni] = *(const bf16x8*)(SB + (size_t)(64 + wn + ni * 16 + l16) * 32 + swzq * 8);
#pragma unroll
        for (int mi = 0; mi < 2; ++mi)
#pragma unroll
            for (int ni = 0; ni < 4; ++ni)
                acc[mi][ni] = __builtin_amdgcn_mfma_f32_16x16x32_bf16(af[mi], bfr[ni], acc[mi][ni], 0, 0, 0);
        __syncthreads();
    }
#pragma unroll
    for (int mi = 0; mi < 2; ++mi)
#pragma unroll
        for (int ni = 0; ni < 4; ++ni)
#pragma unroll
            for (int r = 0; r < 4; ++r) {
                int gm = m0 + wm + mi * 16 + quad * 4 + r;
                int gn = n0 + wn + ni * 16 + l16;
                if (OUT_BF16)
                    ((ushort*)Cv)[(size_t)gm * ldc + gn] = f2bu(acc[mi][ni][r]);
                else
                    ((float*)Cv)[(size_t)gm * ldc + gn] = acc[mi][ni][r];
            }
}

// ---------- pass1f: fused conv (reg ring) + chunk sums + vc MFMA + ucs -------
__global__ __launch_bounds__(128) void pass1f(const ushort* __restrict__ z,
                                              const float* __restrict__ mask,
                                              const float* __restrict__ theta_base,
                                              const float* __restrict__ trs_,
                                              const float* __restrict__ dslopes,
                                              const float* __restrict__ aslopes,
                                              const float* __restrict__ sscale_,
                                              const float* __restrict__ conv_w,
                                              const float* __restrict__ conv_b,
                                              const ushort* __restrict__ W2B,
                                              float* __restrict__ cs_re,
                                              float* __restrict__ cs_im,
                                              float* __restrict__ cs_den,
                                              float* __restrict__ vc,
                                              float* __restrict__ ucs) {
    __shared__ __align__(16) ushort ct[CL_ * CTS_];
    int nc = blockIdx.x, k = blockIdx.y, b = blockIdx.z;
    int hm = threadIdx.x;
    int h = hm >> 2, m = hm & 3;
    int bk = b * K_ + k;
    size_t bkL = (size_t)bk * L_;
    int cxv = k * H_ + h, csc = 2 * D_ + k, cth = 2 * D_ + K_ + k * M_ + m;
    float wx[4], ws4[4], wt4[4];
#pragma unroll
    for (int t = 0; t < 4; ++t) {
        wx[t] = conv_w[t * TOTAL_ + cxv];
        ws4[t] = conv_w[t * TOTAL_ + csc];
        wt4[t] = conv_w[t * TOTAL_ + cth];
    }
    float bx = conv_b[cxv], bs = conv_b[csc], bt = conv_b[cth];
    int l0 = nc * CL_;
    float rx[3], rs[3], rt[3];
#pragma unroll
    for (int j = 0; j < 3; ++j) {
        int ls = l0 - 3 + j;
        if (ls >= 0) {
            size_t zo = (size_t)(b * L_ + ls) * NPAD_;
            rx[j] = b2f(z[zo + cxv]); rs[j] = b2f(z[zo + csc]); rt[j] = b2f(z[zo + cth]);
        } else { rx[j] = 0.f; rs[j] = 0.f; rt[j] = 0.f; }
    }
    float raw = (k < DH_) ? dslopes[k] : aslopes[k - DH_];
    float slope = log1pf(__expf(raw));
    float sscale = sscale_[k], trsv = trs_[k], tb = theta_base[k * M_ + m];
    const float PI3 = 1.04719755119659775f;
    float tw = (k < DH_) ? __expf(-slope * (float)(L_ - 1 - l0)) : __expf(-slope * (float)l0);
    float e_s = (k < DH_) ? __expf(slope) : __expf(-slope);
    float are = 0.f, aim = 0.f, aden = 0.f;
#pragma unroll 4
    for (int i = 0; i < CL_; ++i) {
        int l = l0 + i;
        int row = b * L_ + l;
        size_t zo = (size_t)row * NPAD_;
        float zx = b2f(z[zo + cxv]), zs = b2f(z[zo + csc]), zt = b2f(z[zo + cth]);
        float mval = mask[row];
        float xv = conv4(bx, wx, rx[0], rx[1], rx[2], zx) * mval;
        float s_raw = conv4(bs, ws4, rs[0], rs[1], rs[2], zs) * mval;
        float tr = conv4(bt, wt4, rt[0], rt[1], rt[2], zt);
        rx[0] = rx[1]; rx[1] = rx[2]; rx[2] = zx;
        rs[0] = rs[1]; rs[1] = rs[2]; rs[2] = zs;
        rt[0] = rt[1]; rt[1] = rt[2]; rt[2] = zt;
        float arg = fminf(fmaxf(sscale * s_raw, -20.f), 20.f);
        float p = __expf(arg) * mval;
        float pw = p * tw;
        tw *= e_s;
        float td = tr / (1.f + fabsf(tr));
        float theta = tb + trsv * (td * PI3);
        float phi = xv * theta;
        float sv = __sinf(phi), cv = __cosf(phi);
        unsigned short cu_re = f2bu(pw * cv);
        unsigned short cu_im = f2bu(pw * sv);
        are += b2f(cu_re); aim += b2f(cu_im); aden += pw;
        ct[i * CTS_ + hm] = cu_re;
        ct[i * CTS_ + 128 + hm] = cu_im;
    }
    size_t o = ((size_t)(bk * NC_ + nc)) * 128 + hm;
    cs_re[o] = are;
    cs_im[o] = aim;
    if (hm == 0) cs_den[bk * NC_ + nc] = aden;
    __syncthreads();
    // vc = C_chunk(16x256) @ W''(256x32); wave w -> hout tile w
    int wave = hm >> 6, lane = hm & 63;
    int quad = lane >> 4, l16 = lane & 15;
    f32x4 acc = (f32x4){0.f, 0.f, 0.f, 0.f};
#pragma unroll
    for (int ks = 0; ks < 8; ++ks) {
        bf16x8 af = *(const bf16x8*)(ct + (size_t)l16 * CTS_ + ks * 32 + quad * 8);
        bf16x8 bfr = *(const bf16x8*)(W2B + (size_t)(wave * 16 + l16) * 256 + ks * 32 + quad * 8);
        acc = __builtin_amdgcn_mfma_f32_16x16x32_bf16(af, bfr, acc, 0, 0, 0);
    }
    size_t vbase = (bkL + l0) * 32;
#pragma unroll
    for (int r = 0; r < 4; ++r) {
        int rowv = quad * 4 + r;
        vc[vbase + (size_t)rowv * 32 + wave * 16 + l16] = acc[r];
    }
    // ucs[bk][nc][hout] = chunk sum of vc (for the u-prefix scan)
    float part = acc[0] + acc[1] + acc[2] + acc[3];
    part += __shfl_xor(part, 16, 64);
    part += __shfl_xor(part, 32, 64);
    if (quad == 0) ucs[((size_t)(bk * NC_ + nc)) * 32 + wave * 16 + l16] = part;
}

// ---------- scan2: fused pass2 (cs exclusive scan) + u_prev scan -------------
__global__ void scan2(float* cs_re, float* cs_im, float* cs_den,
                      const float* __restrict__ ucs, float* __restrict__ u_prev) {
    int bid = blockIdx.x, tid = threadIdx.x;
    if (bid < 65) {
        int seq = bid * 256 + tid;
        if (seq >= B_ * K_ * 257) return;
        int bk = seq / 257;
        int ch = seq % 257;
        float* base;
        int stride;
        if (ch < 128) { base = cs_re + (size_t)bk * NC_ * 128 + ch; stride = 128; }
        else if (ch < 256) { base = cs_im + (size_t)bk * NC_ * 128 + (ch - 128); stride = 128; }
        else { base = cs_den + (size_t)bk * NC_; stride = 1; }
        float run = 0.f;
#pragma unroll 4
        for (int i = 0; i < NC_; ++i) {
            float v = base[(size_t)i * stride];
            base[(size_t)i * stride] = run;
            run += v;
        }
    } else {
        int idx = (bid - 65) * 256 + tid;  // 0..2047
        int hout = idx & 31;
        int bk = idx >> 5;
        float run = 0.f;
#pragma unroll 8
        for (int nc = 0; nc < NC_; ++nc) {
            size_t o = ((size_t)bk * NC_ + nc) * 32 + hout;
            float v = ucs[o];
            u_prev[o] = run;
            run += v;
        }
    }
}

// ---------- scan_k7: fused conv + barrier-free scan + norm + gate + store ----
__global__ __launch_bounds__(64) void scan_k7(const ushort* __restrict__ z,
                                              const float* __restrict__ mask,
                                              const float* __restrict__ theta_base,
                                              const float* __restrict__ trs_,
                                              const float* __restrict__ dslopes,
                                              const float* __restrict__ aslopes,
                                              const float* __restrict__ sscale_,
                                              const float* __restrict__ conv_w,
                                              const float* __restrict__ conv_b,
                                              const float* __restrict__ cs_re,
                                              const float* __restrict__ cs_im,
                                              const float* __restrict__ cs_den,
                                              const float* __restrict__ u_prev,
                                              const float* __restrict__ vc,
                                              ushort* __restrict__ gq) {
    int nc = blockIdx.x, k = blockIdx.y, b = blockIdx.z;
    int lane = threadIdx.x;
    int bk = b * K_ + k;
    size_t bkL = (size_t)bk * L_;
    int h0 = lane >> 2, m = lane & 3;
    int hout = lane & 31;
    int c0 = k * H_ + h0, c1 = k * H_ + 16 + h0;
    int csc = 2 * D_ + k, cth = 2 * D_ + K_ + k * M_ + m, cg = D_ + k * H_ + hout;
    float w0[4], w1[4], ws4[4], wt4[4], wg[4];
#pragma unroll
    for (int t = 0; t < 4; ++t) {
        w0[t] = conv_w[t * TOTAL_ + c0];
        w1[t] = conv_w[t * TOTAL_ + c1];
        ws4[t] = conv_w[t * TOTAL_ + csc];
        wt4[t] = conv_w[t * TOTAL_ + cth];
        wg[t] = conv_w[t * TOTAL_ + cg];
    }
    float b0c = conv_b[c0], b1c = conv_b[c1], bsc = conv_b[csc], btc = conv_b[cth], bgc = conv_b[cg];
    int l0 = nc * CL_;
    float r0[3], r1[3], rs[3], rt[3], rg[3];
#pragma unroll
    for (int j = 0; j < 3; ++j) {
        int ls = l0 - 3 + j;
        if (ls >= 0) {
            size_t zo = (size_t)(b * L_ + ls) * NPAD_;
            r0[j] = b2f(z[zo + c0]); r1[j] = b2f(z[zo + c1]); rs[j] = b2f(z[zo + csc]);
            rt[j] = b2f(z[zo + cth]); rg[j] = b2f(z[zo + cg]);
        } else { r0[j] = 0.f; r1[j] = 0.f; rs[j] = 0.f; rt[j] = 0.f; rg[j] = 0.f; }
    }
    float raw = (k < DH_) ? dslopes[k] : aslopes[k - DH_];
    float slope = log1pf(__expf(raw));
    float sscale = sscale_[k], trsv = trs_[k], tb = theta_base[k * M_ + m];
    const float PI3 = 1.04719755119659775f;
    float tw = (k < DH_) ? __expf(-slope * (float)(L_ - 1 - l0)) : __expf(-slope * (float)l0);
    float e_s = (k < DH_) ? __expf(slope) : __expf(-slope);

    size_t o = ((size_t)(bk * NC_ + nc)) * 128;
    float are0 = cs_re[o + lane];
    float are1 = cs_re[o + 64 + lane];
    float aim0 = cs_im[o + lane];
    float aim1 = cs_im[o + 64 + lane];
    float den = cs_den[bk * NC_ + nc];
    float u = u_prev[((size_t)(bk * NC_ + nc)) * 32 + hout];

#pragma unroll 4
    for (int i = 0; i < CL_; ++i) {
        int l = l0 + i;
        int row = b * L_ + l;
        size_t zo = (size_t)row * NPAD_;
        float z0 = b2f(z[zo + c0]), z1 = b2f(z[zo + c1]), zs = b2f(z[zo + csc]);
        float zt = b2f(z[zo + cth]), zg = b2f(z[zo + cg]);
        float mval = mask[row];
        float xv0 = conv4(b0c, w0, r0[0], r0[1], r0[2], z0) * mval;
        float xv1 = conv4(b1c, w1, r1[0], r1[1], r1[2], z1) * mval;
        float s_raw = conv4(bsc, ws4, rs[0], rs[1], rs[2], zs) * mval;
        float tr = conv4(btc, wt4, rt[0], rt[1], rt[2], zt);
        float gpre = conv4(bgc, wg, rg[0], rg[1], rg[2], zg);
        r0[0] = r0[1]; r0[1] = r0[2]; r0[2] = z0;
        r1[0] = r1[1]; r1[1] = r1[2]; r1[2] = z1;
        rs[0] = rs[1]; rs[1] = rs[2]; rs[2] = zs;
        rt[0] = rt[1]; rt[1] = rt[2]; rt[2] = zt;
        rg[0] = rg[1]; rg[1] = rg[2]; rg[2] = zg;
        float arg = fminf(fmaxf(sscale * s_raw, -20.f), 20.f);
        float p = __expf(arg) * mval;
        float pw = p * tw;
        tw *= e_s;
        float td = tr / (1.f + fabsf(tr));
        float theta = tb + trsv * (td * PI3);
        float s0 = __sinf(xv0 * theta), cv0 = __cosf(xv0 * theta);
        float s1 = __sinf(xv1 * theta), cv1 = __cosf(xv1 * theta);
        // bf16-round to match pass1f's sums exactly
        float cre0 = b2f(f2bu(pw * cv0)), cim0 = b2f(f2bu(pw * s0));
        float cre1 = b2f(f2bu(pw * cv1)), cim1 = b2f(f2bu(pw * s1));
        are0 += cre0; aim0 += cim0; are1 += cre1; aim1 += cim1;
        den += pw;
        float s = are0 * are0 + are1 * are1 + aim0 * aim0 + aim1 * aim1;
#pragma unroll
        for (int off = 32; off; off >>= 1) s += __shfl_xor(s, off, 64);
        float inv = 1.f / fmaxf(den, 1e-4f);
        float rsq = rsqrtf(inv * inv * s * (1.0f / 256.0f) + 1e-5f);
        float scv = inv * rsq;
        u += vc[(bkL + l) * 32 + hout];
        float y = scv * u;
        float gate = gpre / (1.f + __expf(-gpre));
        if (lane < 32) gq[(size_t)row * D_ + k * H_ + hout] = f2bu(y * gate);
    }
}

extern "C" void kernel_launch(void* const* d_in, const int* in_sizes, int n_in,
                              void* d_out, int out_size, void* d_ws, size_t ws_size,
                              hipStream_t stream) {
    const float* x = (const float*)d_in[0];
    const float* mask = (const float*)d_in[1];
    const float* W_in = (const float*)d_in[2];
    const float* conv_w = (const float*)d_in[3];
    const float* conv_b = (const float*)d_in[4];
    const float* theta_base = (const float*)d_in[5];
    const float* trs = (const float*)d_in[6];
    const float* dsl = (const float*)d_in[7];
    const float* asl = (const float*)d_in[8];
    const float* ssc = (const float*)d_in[9];
    const float* nsc = (const float*)d_in[10];
    const float* Wre = (const float*)d_in[11];
    const float* Wim = (const float*)d_in[12];
    const float* Wout = (const float*)d_in[13];
    float* out = (float*)d_out;

    char* ws = (char*)d_ws;
    ushort* z     = (ushort*)(ws);                   // 18,874,368
    ushort* x_bf  = (ushort*)(ws + 18874368ULL);     // 8,388,608
    ushort* Wt_in = (ushort*)(ws + 27262976ULL);     // 4,718,592
    ushort* Wt_o  = (ushort*)(ws + 31981568ULL);     // 2,097,152
    ushort* W2B   = (ushort*)(ws + 34078720ULL);     // 16,384
    float* vc     = (float*)(ws + 34095104ULL);      // 16,777,216
    float* cs_re  = (float*)(ws + 50872320ULL);      // 4,194,304
    float* cs_im  = (float*)(ws + 55066624ULL);      // 4,194,304
    float* cs_den = (float*)(ws + 59260928ULL);      // 32,768
    float* ucs    = (float*)(ws + 59293696ULL);      // 1,048,576
    float* u_prev = (float*)(ws + 60342272ULL);      // 1,048,576
    ushort* gq    = (ushort*)(ws + 61390848ULL);     // 8,388,608 (ends 69,779,456)

    prep_all<<<4096 + 576 + 256 + 1, 256, 0, stream>>>(x, W_in, Wout, Wre, Wim, nsc,
                                                       x_bf, Wt_in, Wt_o, W2B);
    gemm_bt64<true><<<dim3(NPAD_ / 128, BL_ / 64), 256, 0, stream>>>(x_bf, Wt_in, z, 1024, NPAD_);
    pass1f<<<dim3(NC_, K_, B_), 128, 0, stream>>>(z, mask, theta_base, trs, dsl, asl, ssc,
                                                  conv_w, conv_b, W2B,
                                                  cs_re, cs_im, cs_den, vc, ucs);
    scan2<<<73, 256, 0, stream>>>(cs_re, cs_im, cs_den, ucs, u_prev);
    scan_k7<<<dim3(NC_, K_, B_), 64, 0, stream>>>(z, mask, theta_base, trs, dsl, asl, ssc,
                                                  conv_w, conv_b, cs_re, cs_im, cs_den,
                                                  u_prev, vc, gq);
    gemm_bt64<false><<<dim3(1024 / 128, BL_ / 64), 256, 0, stream>>>(gq, Wt_o, out, 1024, 1024);
}